// Round 6
// baseline (264.701 us; speedup 1.0000x reference)
//
#include <hip/hip_runtime.h>
#include <hip/hip_bf16.h>

typedef __bf16 bf16;
typedef __bf16 bf16x8 __attribute__((ext_vector_type(8)));
typedef __bf16 bf16x4 __attribute__((ext_vector_type(4)));
typedef float  f32x4  __attribute__((ext_vector_type(4)));
typedef short  short4_t __attribute__((ext_vector_type(4)));

#define LDS_ASYNC16(g, l)                                            \
  __builtin_amdgcn_global_load_lds(                                  \
      (const __attribute__((address_space(1))) void*)(g),            \
      (__attribute__((address_space(3))) void*)(l), 16, 0, 0)

// log2(e) / 32  — folded into Q at GEMM1 epilogue so flash uses exp2 directly
#define QSCALE 0.04508421995f

// ---------------------------------------------------------------- convert (x, w_qkv, w_proj in one launch)
__global__ void cvt3_f32_bf16(const float* __restrict__ i0, bf16* __restrict__ o0, int n0,
                              const float* __restrict__ i1, bf16* __restrict__ o1, int n1,
                              const float* __restrict__ i2, bf16* __restrict__ o2, int n2) {
  int i = blockIdx.x * blockDim.x + threadIdx.x;
  const float* in;
  bf16* out;
  if (i < n0) {
    in = i0; out = o0;
  } else if (i < n0 + n1) {
    i -= n0; in = i1; out = o1;
  } else {
    i -= n0 + n1;
    if (i >= n2) return;
    in = i2; out = o2;
  }
  float4 v = ((const float4*)in)[i];
  bf16x4 o = {(bf16)v.x, (bf16)v.y, (bf16)v.z, (bf16)v.w};
  ((bf16x4*)out)[i] = o;
}

// ---------------------------------------------------------------- GEMM (B^T input)
// C[M,N] = A[M,K] @ B[N,K]^T + bias.  128x128 tile, 4 waves, each 64x64.
// K stepped by 64 as two BK=32 sub-tiles per barrier window.
// MODE 0: write fp32 to outf (row-major M x N)
// MODE 1: qkv split epilogue -> q*QSCALE[B,H,T,hd], k[B,H,T,hd], v^T[B,H,hd,T]
template <int MODE>
__global__ __launch_bounds__(256) void gemm_bt(
    const bf16* __restrict__ A, const bf16* __restrict__ B,
    const float* __restrict__ bias, float* __restrict__ outf,
    bf16* __restrict__ oq, bf16* __restrict__ ok, bf16* __restrict__ ov,
    int M, int N, int K) {
  __shared__ bf16 As[2][128 * 32];
  __shared__ bf16 Bs[2][128 * 32];
  const int tid = threadIdx.x;
  const int wave = tid >> 6, lane = tid & 63;
  const int quad = lane >> 4, l15 = lane & 15;
  const int bm = blockIdx.x * 128, bn = blockIdx.y * 128;
  const int wrow = (wave >> 1) << 6, wcol = (wave & 1) << 6;
  const int srow = tid >> 2;          // staging row 0..63
  const int schunk = (tid & 3) * 8;   // staging element offset within row

  f32x4 acc[4][4] = {};

  const bf16* ga0 = A + (size_t)(bm + srow) * K + schunk;
  const bf16* ga1 = A + (size_t)(bm + srow + 64) * K + schunk;
  const bf16* gb0 = B + (size_t)(bn + srow) * K + schunk;
  const bf16* gb1 = B + (size_t)(bn + srow + 64) * K + schunk;
  char* lA = (char*)As + wave * 1024;  // wave-uniform LDS base (lane*16 appended)
  char* lB = (char*)Bs + wave * 1024;

  for (int k0 = 0; k0 < K; k0 += 64) {
    __syncthreads();
    LDS_ASYNC16(ga0 + k0, lA);
    LDS_ASYNC16(ga1 + k0, lA + 4096);
    LDS_ASYNC16(gb0 + k0, lB);
    LDS_ASYNC16(gb1 + k0, lB + 4096);
    LDS_ASYNC16(ga0 + k0 + 32, lA + 8192);
    LDS_ASYNC16(ga1 + k0 + 32, lA + 8192 + 4096);
    LDS_ASYNC16(gb0 + k0 + 32, lB + 8192);
    LDS_ASYNC16(gb1 + k0 + 32, lB + 8192 + 4096);
    __syncthreads();
#pragma unroll
    for (int s = 0; s < 2; ++s) {
      bf16x8 af[4], bfr[4];
#pragma unroll
      for (int mi = 0; mi < 4; ++mi)
        af[mi] = *(const bf16x8*)&As[s][(wrow + mi * 16 + l15) * 32 + quad * 8];
#pragma unroll
      for (int ni = 0; ni < 4; ++ni)
        bfr[ni] = *(const bf16x8*)&Bs[s][(wcol + ni * 16 + l15) * 32 + quad * 8];
#pragma unroll
      for (int mi = 0; mi < 4; ++mi)
#pragma unroll
        for (int ni = 0; ni < 4; ++ni)
          acc[mi][ni] = __builtin_amdgcn_mfma_f32_16x16x32_bf16(
              af[mi], bfr[ni], acc[mi][ni], 0, 0, 0);
    }
  }

#pragma unroll
  for (int mi = 0; mi < 4; ++mi) {
    const int row0 = bm + wrow + mi * 16 + quad * 4;  // C row = quad*4+reg
#pragma unroll
    for (int ni = 0; ni < 4; ++ni) {
      const int col = bn + wcol + ni * 16 + l15;      // C col = lane&15
      const float bv = bias[col];
      if (MODE == 0) {
#pragma unroll
        for (int r = 0; r < 4; ++r)
          outf[(size_t)(row0 + r) * N + col] = acc[mi][ni][r] + bv;
      } else {
        const int part = col >> 10;  // uniform within a frag (16-col span)
        const int cn = col & 1023, h = cn >> 6, d = cn & 63;
        const int b = row0 >> 11, t0 = row0 & 2047;
        if (part == 2) {  // v -> transposed [bh][d][t], 4 consecutive t pack
          bf16x4 pk = {(bf16)(acc[mi][ni][0] + bv), (bf16)(acc[mi][ni][1] + bv),
                       (bf16)(acc[mi][ni][2] + bv), (bf16)(acc[mi][ni][3] + bv)};
          *(bf16x4*)(ov + ((size_t)(b * 16 + h) * 64 + d) * 2048 + t0) = pk;
        } else {
          const float sc = part ? 1.0f : QSCALE;  // pre-scale Q for exp2 softmax
          bf16* dst = (part ? ok : oq) + ((size_t)(b * 16 + h) * 2048 + t0) * 64 + d;
#pragma unroll
          for (int r = 0; r < 4; ++r)
            dst[(size_t)r * 64] = (bf16)((acc[mi][ni][r] + bv) * sc);
        }
      }
    }
  }
}

// ---------------------------------------------------------------- flash attention
// grid (B*H, 16): block y handles 64-row q-tiles y and 31-y (exactly 33
// key-tile iters per block; 1024 blocks = 4/CU = 16 waves/CU). 4 waves x
// 16 q-rows. Double-buffered K/V, 1 barrier/iter, register prefetch.
// Transpose-free PV: QK^T computed swapped (A=K, B=Q) -> S^T in C-layout
// (row=k-local=quad*4+r, col=q=l15); after exp2 those registers ARE the
// A-fragment of mfma_f32_16x16x16_bf16, so PV needs no P LDS round-trip.
__global__ __launch_bounds__(256) void flash_attn(
    const bf16* __restrict__ qb, const bf16* __restrict__ kb,
    const bf16* __restrict__ vt, bf16* __restrict__ ob) {
  constexpr int T = 2048;
  __shared__ bf16 Ks[2][64 * 72];
  __shared__ bf16 Vs[2][64 * 72];   // transposed: [d][key]
  __shared__ float Ls[4][4][16];    // per-wave l partials [wave][quad][l15]
  const int tid = threadIdx.x, wave = tid >> 6, lane = tid & 63;
  const int quad = lane >> 4, l15 = lane & 15;
  const int bh = blockIdx.x;
  const int b = bh >> 4, h = bh & 15;
  const bf16* qbase = qb + (size_t)bh * T * 64;
  const bf16* kbase = kb + (size_t)bh * T * 64;
  const bf16* vbase = vt + (size_t)bh * 64 * T;
  const int srow = tid >> 3, sc = (tid & 7) * 8;  // srow 0..31

#pragma unroll 1
  for (int half = 0; half < 2; ++half) {
    const int qt = half ? (31 - (int)blockIdx.y) : (int)blockIdx.y;
    const int q0 = qt * 64 + wave * 16;

    bf16x8 qf[2];  // B-operand: Q[q=l15][k=quad*8+j]
#pragma unroll
    for (int ks = 0; ks < 2; ++ks)
      qf[ks] = *(const bf16x8*)(qbase + (size_t)(q0 + l15) * 64 + ks * 32 +
                                quad * 8);

    f32x4 lsumv = {};
    f32x4 oacc[4] = {};  // [di], C-layout row=q-local, col=d-local

    const int nkt = qt + 1;

    // prev half's last tile may share this buffer parity — sync before store
    __syncthreads();
    {
      uint4 k0 = *(const uint4*)(kbase + (size_t)srow * 64 + sc);
      uint4 k1 = *(const uint4*)(kbase + (size_t)(srow + 32) * 64 + sc);
      uint4 v0 = *(const uint4*)(vbase + (size_t)srow * T + sc);
      uint4 v1 = *(const uint4*)(vbase + (size_t)(srow + 32) * T + sc);
      *(uint4*)&Ks[0][srow * 72 + sc] = k0;
      *(uint4*)&Ks[0][(srow + 32) * 72 + sc] = k1;
      *(uint4*)&Vs[0][srow * 72 + sc] = v0;
      *(uint4*)&Vs[0][(srow + 32) * 72 + sc] = v1;
    }

#pragma unroll 1
    for (int kt = 0; kt < nkt; ++kt) {
      __syncthreads();  // cur buffer writes visible; prev reads done
      const int cur = kt & 1;
      const bool pre = (kt + 1) < nkt;
      uint4 pk0, pk1, pv0, pv1;
      if (pre) {  // prefetch next tile into registers (overlaps compute)
        const bf16* kp = kbase + (size_t)(kt + 1) * 64 * 64;
        const bf16* vp = vbase + (kt + 1) * 64;
        pk0 = *(const uint4*)(kp + (size_t)srow * 64 + sc);
        pk1 = *(const uint4*)(kp + (size_t)(srow + 32) * 64 + sc);
        pv0 = *(const uint4*)(vp + (size_t)srow * T + sc);
        pv1 = *(const uint4*)(vp + (size_t)(srow + 32) * T + sc);
      }
      // S^T = K·Q^T : st[ki], row=k-local(quad*4+r), col=q(l15)
      f32x4 st[4];
#pragma unroll
      for (int ki = 0; ki < 4; ++ki) {
        bf16x8 kfa = *(const bf16x8*)&Ks[cur][(ki * 16 + l15) * 72 + quad * 8];
        bf16x8 kfb =
            *(const bf16x8*)&Ks[cur][(ki * 16 + l15) * 72 + 32 + quad * 8];
        f32x4 a = {0.f, 0.f, 0.f, 0.f};
        a = __builtin_amdgcn_mfma_f32_16x16x32_bf16(kfa, qf[0], a, 0, 0, 0);
        a = __builtin_amdgcn_mfma_f32_16x16x32_bf16(kfb, qf[1], a, 0, 0, 0);
        st[ki] = a;
      }
      if (kt == qt) {  // mask only the diagonal tile
#pragma unroll
        for (int ki = 0; ki < 4; ++ki)
#pragma unroll
          for (int r = 0; r < 4; ++r) {
            const int kcol = kt * 64 + ki * 16 + quad * 4 + r;
            const int qrow = q0 + l15;
            if (kcol > qrow) st[ki][r] = -__builtin_inff();
          }
      }
      // p = exp2(s); per-lane partial row sums (q=l15)
      short4_t pa[4];
#pragma unroll
      for (int ki = 0; ki < 4; ++ki) {
#pragma unroll
        for (int r = 0; r < 4; ++r)
          st[ki][r] = __builtin_amdgcn_exp2f(st[ki][r]);
        lsumv += st[ki];
        bf16x4 pk = {(bf16)st[ki][0], (bf16)st[ki][1], (bf16)st[ki][2],
                     (bf16)st[ki][3]};
        pa[ki] = __builtin_bit_cast(short4_t, pk);
      }
      // PV: O[q][d] += P·V via 16x16x16 (P-regs are the A-fragment)
#pragma unroll
      for (int di = 0; di < 4; ++di)
#pragma unroll
        for (int ki = 0; ki < 4; ++ki) {
          bf16x4 vv = *(const bf16x4*)&Vs[cur][(di * 16 + l15) * 72 + ki * 16 +
                                              quad * 4];
          short4_t vb = __builtin_bit_cast(short4_t, vv);
          oacc[di] = __builtin_amdgcn_mfma_f32_16x16x16bf16_1k(pa[ki], vb,
                                                               oacc[di], 0, 0, 0);
        }
      if (pre) {  // write prefetched tile into the other buffer
        const int nxt = cur ^ 1;
        *(uint4*)&Ks[nxt][srow * 72 + sc] = pk0;
        *(uint4*)&Ks[nxt][(srow + 32) * 72 + sc] = pk1;
        *(uint4*)&Vs[nxt][srow * 72 + sc] = pv0;
        *(uint4*)&Vs[nxt][(srow + 32) * 72 + sc] = pv1;
      }
    }

    // epilogue: transpose l partials (q=l15 -> q=quad*4+r), divide, store
    Ls[wave][quad][l15] = lsumv[0] + lsumv[1] + lsumv[2] + lsumv[3];
    // wave-private region; compiler inserts lgkmcnt before dependent reads
#pragma unroll
    for (int r = 0; r < 4; ++r) {
      const int rloc = quad * 4 + r;
      const float l = Ls[wave][0][rloc] + Ls[wave][1][rloc] +
                      Ls[wave][2][rloc] + Ls[wave][3][rloc];
      const float inv = 1.f / l;
      const int t = q0 + rloc;
#pragma unroll
      for (int di = 0; di < 4; ++di) {
        const int d = di * 16 + l15;
        ob[((size_t)b * 2048 + t) * 1024 + h * 64 + d] =
            (bf16)(oacc[di][r] * inv);
      }
    }
  }
}

// ---------------------------------------------------------------- launch
extern "C" void kernel_launch(void* const* d_in, const int* in_sizes, int n_in,
                              void* d_out, int out_size, void* d_ws,
                              size_t ws_size, hipStream_t stream) {
  const float* x = (const float*)d_in[0];
  const float* w_qkv = (const float*)d_in[1];
  const float* b_qkv = (const float*)d_in[2];
  const float* w_proj = (const float*)d_in[3];
  const float* b_proj = (const float*)d_in[4];
  float* out = (float*)d_out;

  const int B = 4, T = 2048, C = 1024;
  const size_t nx = (size_t)B * T * C;  // 8388608

  char* ws = (char*)d_ws;
  bf16* xb = (bf16*)ws;      ws += nx * 2;
  bf16* wqkvb = (bf16*)ws;   ws += (size_t)3 * C * C * 2;
  bf16* wprojb = (bf16*)ws;  ws += (size_t)C * C * 2;
  bf16* qb = (bf16*)ws;      ws += nx * 2;
  bf16* kbuf = (bf16*)ws;    ws += nx * 2;
  bf16* vtb = (bf16*)ws;     ws += nx * 2;
  bf16* attb = (bf16*)ws;    ws += nx * 2;   // total 88 MB

  const int n0 = (int)(nx / 4), n1 = 3 * C * C / 4, n2 = C * C / 4;
  cvt3_f32_bf16<<<(n0 + n1 + n2 + 255) / 256, 256, 0, stream>>>(
      x, xb, n0, w_qkv, wqkvb, n1, w_proj, wprojb, n2);

  dim3 g1(64, 24);  // M/128, 3C/128
  gemm_bt<1><<<g1, 256, 0, stream>>>(xb, wqkvb, b_qkv, nullptr, qb, kbuf, vtb,
                                     B * T, 3 * C, C);
  dim3 g2(64, 16);  // B*H, paired 64-row q-tiles
  flash_attn<<<g2, 256, 0, stream>>>(qb, kbuf, vtb, attb);

  dim3 g3(64, 8);   // M/128, C/128
  gemm_bt<0><<<g3, 256, 0, stream>>>(attb, wprojb, b_proj, out, nullptr,
                                     nullptr, nullptr, B * T, C, C);
}

// Round 7
// 251.437 us; speedup vs baseline: 1.0528x; 1.0528x over previous
//
#include <hip/hip_runtime.h>
#include <hip/hip_bf16.h>

typedef __bf16 bf16;
typedef __bf16 bf16x8 __attribute__((ext_vector_type(8)));
typedef __bf16 bf16x4 __attribute__((ext_vector_type(4)));
typedef float  f32x4  __attribute__((ext_vector_type(4)));
typedef short  short4_t __attribute__((ext_vector_type(4)));

#define LDS_ASYNC16(g, l)                                            \
  __builtin_amdgcn_global_load_lds(                                  \
      (const __attribute__((address_space(1))) void*)(g),            \
      (__attribute__((address_space(3))) void*)(l), 16, 0, 0)

// log2(e) / 32  — folded into Q at GEMM1 epilogue so flash uses exp2 directly
#define QSCALE 0.04508421995f

// ---------------------------------------------------------------- convert (x, w_qkv, w_proj in one launch)
__global__ void cvt3_f32_bf16(const float* __restrict__ i0, bf16* __restrict__ o0, int n0,
                              const float* __restrict__ i1, bf16* __restrict__ o1, int n1,
                              const float* __restrict__ i2, bf16* __restrict__ o2, int n2) {
  int i = blockIdx.x * blockDim.x + threadIdx.x;
  const float* in;
  bf16* out;
  if (i < n0) {
    in = i0; out = o0;
  } else if (i < n0 + n1) {
    i -= n0; in = i1; out = o1;
  } else {
    i -= n0 + n1;
    if (i >= n2) return;
    in = i2; out = o2;
  }
  float4 v = ((const float4*)in)[i];
  bf16x4 o = {(bf16)v.x, (bf16)v.y, (bf16)v.z, (bf16)v.w};
  ((bf16x4*)out)[i] = o;
}

// ---------------------------------------------------------------- GEMM (B^T input)
// C[M,N] = A[M,K] @ B[N,K]^T + bias.  128x128 tile, 4 waves, each 64x64.
// K stepped by 64 as two BK=32 sub-tiles per barrier window.
// MODE 0: write fp32 to outf (row-major M x N)
// MODE 1: qkv split epilogue -> q*QSCALE[B,H,T,hd], k[B,H,T,hd], v^T[B,H,hd,T]
template <int MODE>
__global__ __launch_bounds__(256) void gemm_bt(
    const bf16* __restrict__ A, const bf16* __restrict__ B,
    const float* __restrict__ bias, float* __restrict__ outf,
    bf16* __restrict__ oq, bf16* __restrict__ ok, bf16* __restrict__ ov,
    int M, int N, int K) {
  __shared__ bf16 As[2][128 * 32];
  __shared__ bf16 Bs[2][128 * 32];
  const int tid = threadIdx.x;
  const int wave = tid >> 6, lane = tid & 63;
  const int quad = lane >> 4, l15 = lane & 15;
  const int bm = blockIdx.x * 128, bn = blockIdx.y * 128;
  const int wrow = (wave >> 1) << 6, wcol = (wave & 1) << 6;
  const int srow = tid >> 2;          // staging row 0..63
  const int schunk = (tid & 3) * 8;   // staging element offset within row

  f32x4 acc[4][4] = {};

  const bf16* ga0 = A + (size_t)(bm + srow) * K + schunk;
  const bf16* ga1 = A + (size_t)(bm + srow + 64) * K + schunk;
  const bf16* gb0 = B + (size_t)(bn + srow) * K + schunk;
  const bf16* gb1 = B + (size_t)(bn + srow + 64) * K + schunk;
  char* lA = (char*)As + wave * 1024;  // wave-uniform LDS base (lane*16 appended)
  char* lB = (char*)Bs + wave * 1024;

  for (int k0 = 0; k0 < K; k0 += 64) {
    __syncthreads();
    LDS_ASYNC16(ga0 + k0, lA);
    LDS_ASYNC16(ga1 + k0, lA + 4096);
    LDS_ASYNC16(gb0 + k0, lB);
    LDS_ASYNC16(gb1 + k0, lB + 4096);
    LDS_ASYNC16(ga0 + k0 + 32, lA + 8192);
    LDS_ASYNC16(ga1 + k0 + 32, lA + 8192 + 4096);
    LDS_ASYNC16(gb0 + k0 + 32, lB + 8192);
    LDS_ASYNC16(gb1 + k0 + 32, lB + 8192 + 4096);
    __syncthreads();
#pragma unroll
    for (int s = 0; s < 2; ++s) {
      bf16x8 af[4], bfr[4];
#pragma unroll
      for (int mi = 0; mi < 4; ++mi)
        af[mi] = *(const bf16x8*)&As[s][(wrow + mi * 16 + l15) * 32 + quad * 8];
#pragma unroll
      for (int ni = 0; ni < 4; ++ni)
        bfr[ni] = *(const bf16x8*)&Bs[s][(wcol + ni * 16 + l15) * 32 + quad * 8];
#pragma unroll
      for (int mi = 0; mi < 4; ++mi)
#pragma unroll
        for (int ni = 0; ni < 4; ++ni)
          acc[mi][ni] = __builtin_amdgcn_mfma_f32_16x16x32_bf16(
              af[mi], bfr[ni], acc[mi][ni], 0, 0, 0);
    }
  }

#pragma unroll
  for (int mi = 0; mi < 4; ++mi) {
    const int row0 = bm + wrow + mi * 16 + quad * 4;  // C row = quad*4+reg
#pragma unroll
    for (int ni = 0; ni < 4; ++ni) {
      const int col = bn + wcol + ni * 16 + l15;      // C col = lane&15
      const float bv = bias[col];
      if (MODE == 0) {
#pragma unroll
        for (int r = 0; r < 4; ++r)
          outf[(size_t)(row0 + r) * N + col] = acc[mi][ni][r] + bv;
      } else {
        const int part = col >> 10;  // uniform within a frag (16-col span)
        const int cn = col & 1023, h = cn >> 6, d = cn & 63;
        const int b = row0 >> 11, t0 = row0 & 2047;
        if (part == 2) {  // v -> transposed [bh][d][t], 4 consecutive t pack
          bf16x4 pk = {(bf16)(acc[mi][ni][0] + bv), (bf16)(acc[mi][ni][1] + bv),
                       (bf16)(acc[mi][ni][2] + bv), (bf16)(acc[mi][ni][3] + bv)};
          *(bf16x4*)(ov + ((size_t)(b * 16 + h) * 64 + d) * 2048 + t0) = pk;
        } else {
          const float sc = part ? 1.0f : QSCALE;  // pre-scale Q for exp2 softmax
          bf16* dst = (part ? ok : oq) + ((size_t)(b * 16 + h) * 2048 + t0) * 64 + d;
#pragma unroll
          for (int r = 0; r < 4; ++r)
            dst[(size_t)r * 64] = (bf16)((acc[mi][ni][r] + bv) * sc);
        }
      }
    }
  }
}

// ---------------------------------------------------------------- flash attention
// grid (B*H, 16), one 128-row q-tile per block, qt = 15 - blockIdx.y so the
// heavy (long-K) tiles dispatch FIRST and cheap tiles pack the tail.
// 1024 blocks = 4 blocks/CU co-resident (LDS 38.9KB x4 <= 160KB, VGPR<=128)
// -> 16 waves/CU, keeping R5's 128-row amortization (R6 lesson: q-rows per
// block is the amortization lever; don't trade it for occupancy).
// 4 waves x 32 q-rows; 64-key tiles; double-buffered K/V, 1 barrier/iter,
// register prefetch. Transpose-free PV: QK^T computed swapped (A=K, B=Q) ->
// S^T in C-layout (row=k-local=quad*4+r, col=q=l15); after exp2 those
// registers ARE the A-fragment of mfma_f32_16x16x16_bf16.
__global__ __launch_bounds__(256) void flash_attn(
    const bf16* __restrict__ qb, const bf16* __restrict__ kb,
    const bf16* __restrict__ vt, bf16* __restrict__ ob) {
  constexpr int T = 2048;
  __shared__ bf16 Ks[2][64 * 72];
  __shared__ bf16 Vs[2][64 * 72];      // transposed: [d][key]
  __shared__ float Ls[4][2][4][16];    // per-wave l partials
  const int tid = threadIdx.x, wave = tid >> 6, lane = tid & 63;
  const int quad = lane >> 4, l15 = lane & 15;
  const int bh = blockIdx.x;
  const int b = bh >> 4, h = bh & 15;
  const bf16* qbase = qb + (size_t)bh * T * 64;
  const bf16* kbase = kb + (size_t)bh * T * 64;
  const bf16* vbase = vt + (size_t)bh * 64 * T;
  const int srow = tid >> 3, sc = (tid & 7) * 8;  // srow 0..31

  const int qt = 15 - (int)blockIdx.y;  // heavy tiles first
  const int q0 = qt * 128 + wave * 32;

  bf16x8 qf[2][2];  // B-operand: Q[q=l15][k=quad*8+j]
#pragma unroll
  for (int qi = 0; qi < 2; ++qi)
#pragma unroll
    for (int ks = 0; ks < 2; ++ks)
      qf[qi][ks] = *(const bf16x8*)(qbase + (size_t)(q0 + qi * 16 + l15) * 64 +
                                    ks * 32 + quad * 8);

  f32x4 lsumv[2] = {};
  f32x4 oacc[2][4] = {};  // [qi][di], C-layout row=q-local, col=d-local

  const int nkt = 2 * qt + 2;
  const int ktp = q0 >> 6;  // this wave's diagonal tile

  // prologue: stage tile 0 into buffer 0
  {
    uint4 k0 = *(const uint4*)(kbase + (size_t)srow * 64 + sc);
    uint4 k1 = *(const uint4*)(kbase + (size_t)(srow + 32) * 64 + sc);
    uint4 v0 = *(const uint4*)(vbase + (size_t)srow * T + sc);
    uint4 v1 = *(const uint4*)(vbase + (size_t)(srow + 32) * T + sc);
    *(uint4*)&Ks[0][srow * 72 + sc] = k0;
    *(uint4*)&Ks[0][(srow + 32) * 72 + sc] = k1;
    *(uint4*)&Vs[0][srow * 72 + sc] = v0;
    *(uint4*)&Vs[0][(srow + 32) * 72 + sc] = v1;
  }

#pragma unroll 1
  for (int kt = 0; kt < nkt; ++kt) {
    __syncthreads();  // cur buffer writes visible; prev reads done
    const int cur = kt & 1;
    const bool pre = (kt + 1) < nkt;
    uint4 pk0, pk1, pv0, pv1;
    if (pre) {  // prefetch next tile into registers (overlaps compute)
      const bf16* kp = kbase + (size_t)(kt + 1) * 64 * 64;
      const bf16* vp = vbase + (kt + 1) * 64;
      pk0 = *(const uint4*)(kp + (size_t)srow * 64 + sc);
      pk1 = *(const uint4*)(kp + (size_t)(srow + 32) * 64 + sc);
      pv0 = *(const uint4*)(vp + (size_t)srow * T + sc);
      pv1 = *(const uint4*)(vp + (size_t)(srow + 32) * T + sc);
    }
    if (kt <= ktp) {
      // S^T = K·Q^T : st[ki][qi], row=k-local(quad*4+r), col=q(l15)
      f32x4 st[4][2];
#pragma unroll
      for (int ki = 0; ki < 4; ++ki) {
        bf16x8 kfa = *(const bf16x8*)&Ks[cur][(ki * 16 + l15) * 72 + quad * 8];
        bf16x8 kfb =
            *(const bf16x8*)&Ks[cur][(ki * 16 + l15) * 72 + 32 + quad * 8];
#pragma unroll
        for (int qi = 0; qi < 2; ++qi) {
          f32x4 a = {0.f, 0.f, 0.f, 0.f};
          a = __builtin_amdgcn_mfma_f32_16x16x32_bf16(kfa, qf[qi][0], a, 0, 0, 0);
          a = __builtin_amdgcn_mfma_f32_16x16x32_bf16(kfb, qf[qi][1], a, 0, 0, 0);
          st[ki][qi] = a;
        }
      }
      if (kt == ktp) {  // mask only the diagonal tile
#pragma unroll
        for (int ki = 0; ki < 4; ++ki)
#pragma unroll
          for (int qi = 0; qi < 2; ++qi)
#pragma unroll
            for (int r = 0; r < 4; ++r) {
              const int kcol = kt * 64 + ki * 16 + quad * 4 + r;
              const int qrow = q0 + qi * 16 + l15;
              if (kcol > qrow) st[ki][qi][r] = -__builtin_inff();
            }
      }
      // p = exp2(s); per-lane partial row sums (q=l15)
      short4_t pa[4][2];
#pragma unroll
      for (int ki = 0; ki < 4; ++ki)
#pragma unroll
        for (int qi = 0; qi < 2; ++qi) {
#pragma unroll
          for (int r = 0; r < 4; ++r)
            st[ki][qi][r] = __builtin_amdgcn_exp2f(st[ki][qi][r]);
          lsumv[qi] += st[ki][qi];
          bf16x4 pk = {(bf16)st[ki][qi][0], (bf16)st[ki][qi][1],
                       (bf16)st[ki][qi][2], (bf16)st[ki][qi][3]};
          pa[ki][qi] = __builtin_bit_cast(short4_t, pk);
        }
      // PV: O[q][d] += P·V via 16x16x16 (P-regs are the A-fragment)
#pragma unroll
      for (int di = 0; di < 4; ++di)
#pragma unroll
        for (int ki = 0; ki < 4; ++ki) {
          bf16x4 vv = *(const bf16x4*)&Vs[cur][(di * 16 + l15) * 72 + ki * 16 +
                                              quad * 4];
          short4_t vb = __builtin_bit_cast(short4_t, vv);
#pragma unroll
          for (int qi = 0; qi < 2; ++qi)
            oacc[qi][di] = __builtin_amdgcn_mfma_f32_16x16x16bf16_1k(
                pa[ki][qi], vb, oacc[qi][di], 0, 0, 0);
        }
    }
    if (pre) {  // write prefetched tile into the other buffer
      const int nxt = cur ^ 1;
      *(uint4*)&Ks[nxt][srow * 72 + sc] = pk0;
      *(uint4*)&Ks[nxt][(srow + 32) * 72 + sc] = pk1;
      *(uint4*)&Vs[nxt][srow * 72 + sc] = pv0;
      *(uint4*)&Vs[nxt][(srow + 32) * 72 + sc] = pv1;
    }
  }

  // epilogue: transpose l partials (q=l15 -> q=quad*4+r), divide, store
#pragma unroll
  for (int qi = 0; qi < 2; ++qi)
    Ls[wave][qi][quad][l15] =
        lsumv[qi][0] + lsumv[qi][1] + lsumv[qi][2] + lsumv[qi][3];
  // wave-private region; compiler inserts lgkmcnt before dependent reads
#pragma unroll
  for (int qi = 0; qi < 2; ++qi)
#pragma unroll
    for (int r = 0; r < 4; ++r) {
      const int rloc = quad * 4 + r;
      const float l = Ls[wave][qi][0][rloc] + Ls[wave][qi][1][rloc] +
                      Ls[wave][qi][2][rloc] + Ls[wave][qi][3][rloc];
      const float inv = 1.f / l;
      const int t = q0 + qi * 16 + rloc;
#pragma unroll
      for (int di = 0; di < 4; ++di) {
        const int d = di * 16 + l15;
        ob[((size_t)b * 2048 + t) * 1024 + h * 64 + d] =
            (bf16)(oacc[qi][di][r] * inv);
      }
    }
}

// ---------------------------------------------------------------- launch
extern "C" void kernel_launch(void* const* d_in, const int* in_sizes, int n_in,
                              void* d_out, int out_size, void* d_ws,
                              size_t ws_size, hipStream_t stream) {
  const float* x = (const float*)d_in[0];
  const float* w_qkv = (const float*)d_in[1];
  const float* b_qkv = (const float*)d_in[2];
  const float* w_proj = (const float*)d_in[3];
  const float* b_proj = (const float*)d_in[4];
  float* out = (float*)d_out;

  const int B = 4, T = 2048, C = 1024;
  const size_t nx = (size_t)B * T * C;  // 8388608

  char* ws = (char*)d_ws;
  bf16* xb = (bf16*)ws;      ws += nx * 2;
  bf16* wqkvb = (bf16*)ws;   ws += (size_t)3 * C * C * 2;
  bf16* wprojb = (bf16*)ws;  ws += (size_t)C * C * 2;
  bf16* qb = (bf16*)ws;      ws += nx * 2;
  bf16* kbuf = (bf16*)ws;    ws += nx * 2;
  bf16* vtb = (bf16*)ws;     ws += nx * 2;
  bf16* attb = (bf16*)ws;    ws += nx * 2;   // total 88 MB

  const int n0 = (int)(nx / 4), n1 = 3 * C * C / 4, n2 = C * C / 4;
  cvt3_f32_bf16<<<(n0 + n1 + n2 + 255) / 256, 256, 0, stream>>>(
      x, xb, n0, w_qkv, wqkvb, n1, w_proj, wprojb, n2);

  dim3 g1(64, 24);  // M/128, 3C/128
  gemm_bt<1><<<g1, 256, 0, stream>>>(xb, wqkvb, b_qkv, nullptr, qb, kbuf, vtb,
                                     B * T, 3 * C, C);
  dim3 g2(64, 16);  // B*H, one q-tile per block, heavy first
  flash_attn<<<g2, 256, 0, stream>>>(qb, kbuf, vtb, attb);

  dim3 g3(64, 8);   // M/128, C/128
  gemm_bt<0><<<g3, 256, 0, stream>>>(attb, wprojb, b_proj, out, nullptr,
                                     nullptr, nullptr, B * T, C, C);
}